// Round 1
// baseline (267.143 us; speedup 1.0000x reference)
//
#include <hip/hip_runtime.h>
#include <hip/hip_bf16.h>
#include <math.h>

#define B_ 1024
#define S_ 200
#define D_ 128
#define H_ 128
#define N_ 64
#define SP_ 208   // S padded to 13*16 MFMA rows

typedef __attribute__((ext_vector_type(8))) short short8;
typedef __attribute__((ext_vector_type(8))) __bf16 bf16x8;
typedef __attribute__((ext_vector_type(4))) float floatx4;

static __device__ __forceinline__ float bf2f(unsigned short u) {
    union { unsigned int i; float f; } v; v.i = ((unsigned int)u) << 16; return v.f;
}
static __device__ __forceinline__ unsigned short f2bf(float f) {
    union { float f; unsigned int u; } v; v.f = f;
    unsigned int u = v.u;
    return (unsigned short)((u + 0x7FFFu + ((u >> 16) & 1u)) >> 16);   // RNE
}
static __device__ __forceinline__ float ld1(const void* p, int isbf, size_t i) {
    return isbf ? bf2f(((const unsigned short*)p)[i]) : ((const float*)p)[i];
}
static __device__ __forceinline__ float fast_tanh(float x) {
    float t = __expf(2.0f * x);
    return 1.0f - 2.0f * __builtin_amdgcn_rcpf(t + 1.0f);   // err ~2e-5
}

// ---------------- K-1: dtype detection ----------------
__global__ __launch_bounds__(64) void detect_kernel(
    const void* a0, const void* a1, const void* a2, const void* a3,
    const void* a4, const void* a5, const void* a6, const void* a7,
    int* flags)
{
    int bid = blockIdx.x, t = threadIdx.x;
    if (bid == 3) {
        const unsigned char* mb = (const unsigned char*)a3;
        int f = 0;
        for (int i = t; i < 4096; i += 64)
            if ((i & 3) && mb[i]) f = 1;
        for (int off = 32; off; off >>= 1) f |= __shfl_xor(f, off, 64);
        if (t == 0) flags[3] = f;          // 1 => uint8 mask, 0 => int32 mask
        return;
    }
    const void* ptrs[8] = {a0, a1, a2, a3, a4, a5, a6, a7};
    const int counts[8] = {B_*S_*D_, S_*D_, B_*D_, 0, B_*N_*D_, D_*H_, D_*H_, H_};
    const unsigned int* w = (const unsigned int*)ptrs[bid];
    int words = counts[bid] / 2; if (words > 1024) words = 1024;
    int pass = 0, tot = 0;
    for (int i = t; i < words; i += 64) {
        unsigned int e = (w[i] >> 7) & 0xFF;
        tot++;
        if (e == 0 || (e >= 96 && e <= 140)) pass++;
    }
    for (int off = 32; off; off >>= 1) {
        pass += __shfl_xor(pass, off, 64);
        tot  += __shfl_xor(tot,  off, 64);
    }
    if (t == 0) flags[bid] = (pass * 4 >= tot * 3) ? 1 : 0;
}

// ---------------- prep: block 0 -> WeTf (fragment-swizzled) + pbT pad; blocks 1..200 -> pbT cols
// WeTf layout: frag = nt*4+kks; WeTf[(frag*64+lane)*8+j] = We[kks*32+(lane>>4)*8+j][nt*16+(lane&15)]
// pbT layout: pbT[h*SP_ + s] = (pos @ Wp)[s][h]; rows s=200..207 zeroed.
__global__ __launch_bounds__(128) void prep_kernel(
    const void* __restrict__ We, const void* __restrict__ pos,
    const void* __restrict__ Wp, const int* __restrict__ flags,
    unsigned short* __restrict__ WeTf, float* __restrict__ pbT)
{
    int blk = blockIdx.x, t = threadIdx.x;
    __shared__ unsigned short T[128][136];
    __shared__ float prow[D_];
    if (blk == 0) {
        int fWe = flags[6];
        for (int c = t; c < 2048; c += 128) {
            int d = c >> 4, h8 = (c & 15) * 8;
            short8 v;
            if (fWe) {
                v = *(const short8*)((const unsigned short*)We + d * H_ + h8);
            } else {
                const float* p = (const float*)We + d * H_ + h8;
                float4 a = ((const float4*)p)[0], b = ((const float4*)p)[1];
                v[0] = (short)f2bf(a.x); v[1] = (short)f2bf(a.y);
                v[2] = (short)f2bf(a.z); v[3] = (short)f2bf(a.w);
                v[4] = (short)f2bf(b.x); v[5] = (short)f2bf(b.y);
                v[6] = (short)f2bf(b.z); v[7] = (short)f2bf(b.w);
            }
            *(short8*)(&T[d][h8]) = v;
        }
        __syncthreads();
        for (int i = t; i < 2048; i += 128) {
            int frag = i >> 6, ln = i & 63;
            int nt = frag >> 2, kks = frag & 3;
            int h = nt * 16 + (ln & 15);
            int dbase = kks * 32 + (ln >> 4) * 8;
            short8 v;
#pragma unroll
            for (int j = 0; j < 8; ++j) v[j] = (short)T[dbase + j][h];
            *(short8*)(WeTf + (size_t)i * 8) = v;
        }
        // zero-pad pbT rows 200..207 for every h
        for (int i = t; i < H_ * (SP_ - S_); i += 128) {
            int h = i >> 3, s2 = S_ + (i & 7);
            pbT[(size_t)h * SP_ + s2] = 0.f;
        }
    } else {
        int s = blk - 1, h = t;
        prow[h] = ld1(pos, flags[1], (size_t)s * D_ + h);
        __syncthreads();
        float acc = 0.f;
        if (flags[5]) {
            const unsigned short* W = (const unsigned short*)Wp;
            for (int d = 0; d < D_; ++d) acc = fmaf(prow[d], bf2f(W[d * H_ + h]), acc);
        } else {
            const float* W = (const float*)Wp;
            for (int d = 0; d < D_; ++d) acc = fmaf(prow[d], W[d * H_ + h], acc);
        }
        pbT[(size_t)h * SP_ + s] = acc;
    }
}

// ---------------- fused: per-b scores GEMM + softmax + weighted sum + losses ----------------
// Block = 512 thr (8 waves), one b per block. X[b] staged in LDS (bf16, XOR-swizzled).
// Wave w owns ntile nt=w (h = w*16 + (lane&15)); its 4 We-fragments live in registers.
__global__ __launch_bounds__(512, 4) void fused_kernel(
    const void* __restrict__ Xs, const void* __restrict__ Xitem,
    const void* __restrict__ maskv, const void* __restrict__ origin,
    const unsigned short* __restrict__ WeTf, const float* __restrict__ pbT,
    const void* __restrict__ zv, const int* __restrict__ flags,
    float* __restrict__ pos_loss, float* __restrict__ neg_sum,
    float* __restrict__ out)
{
    int b = blockIdx.x, t = threadIdx.x;
    int wv = t >> 6, lane = t & 63;
    int quad = lane >> 4, mrow = lane & 15;
    int fXs = flags[0], fXi = flags[2], fMk = flags[3], fOr = flags[4], fz = flags[7];

    // LDS element (s,d) lives at Xsh[s*128 + (d ^ ((s&7)<<3))]  (16B-slot XOR swizzle)
    __shared__ __align__(16) unsigned short Xsh[SP_ * D_];   // 53248 B
    __shared__ float smemU[2048];       // sp[8][208] | partial[16][128] | p_oo/p_ov[8][64]
    __shared__ float attn[256];
    __shared__ float att_out[D_], lastv[D_], outv[D_];
    __shared__ float red[24];
    __shared__ int redi[8];
    __shared__ float sc1s, sc2s, vvs;

    // --- origin preload: thread -> (n = t>>3, eighth-of-D = t&7), 16 f32 regs ---
    int nn = t >> 3, part = t & 7;
    float o_f[16];
    if (fOr) {
        const unsigned short* p = (const unsigned short*)origin + ((size_t)b * N_ + nn) * D_ + part * 16;
#pragma unroll
        for (int j = 0; j < 2; ++j) {
            uint4 u = *(const uint4*)(p + j * 8);
            o_f[j*8+0] = bf2f((unsigned short)(u.x & 0xffff));
            o_f[j*8+1] = bf2f((unsigned short)(u.x >> 16));
            o_f[j*8+2] = bf2f((unsigned short)(u.y & 0xffff));
            o_f[j*8+3] = bf2f((unsigned short)(u.y >> 16));
            o_f[j*8+4] = bf2f((unsigned short)(u.z & 0xffff));
            o_f[j*8+5] = bf2f((unsigned short)(u.z >> 16));
            o_f[j*8+6] = bf2f((unsigned short)(u.w & 0xffff));
            o_f[j*8+7] = bf2f((unsigned short)(u.w >> 16));
        }
    } else {
        const float* p = (const float*)origin + ((size_t)b * N_ + nn) * D_ + part * 16;
#pragma unroll
        for (int j = 0; j < 4; ++j) {
            float4 v = *(const float4*)(p + j * 4);
            o_f[j*4+0] = v.x; o_f[j*4+1] = v.y; o_f[j*4+2] = v.z; o_f[j*4+3] = v.w;
        }
    }

    // --- stage X[b] -> LDS bf16, 16B chunks, swizzled; rows 200..207 zeroed ---
    for (int i = t; i < SP_ * 16; i += 512) {
        int s = i >> 4, c8 = (i & 15) * 8;
        short8 v;
        if (s >= S_) {
#pragma unroll
            for (int j = 0; j < 8; ++j) v[j] = 0;
        } else if (fXs) {
            v = *(const short8*)((const unsigned short*)Xs + ((size_t)b * S_ + s) * D_ + c8);
        } else {
            const float* p = (const float*)Xs + ((size_t)b * S_ + s) * D_ + c8;
            float4 a = ((const float4*)p)[0], c = ((const float4*)p)[1];
            v[0] = (short)f2bf(a.x); v[1] = (short)f2bf(a.y);
            v[2] = (short)f2bf(a.z); v[3] = (short)f2bf(a.w);
            v[4] = (short)f2bf(c.x); v[5] = (short)f2bf(c.y);
            v[6] = (short)f2bf(c.z); v[7] = (short)f2bf(c.w);
        }
        *(short8*)(Xsh + s * D_ + (c8 ^ ((s & 7) << 3))) = v;
    }

    // --- this wave's B fragments (registers) + z + pb column base ---
    int nt = wv;
    bf16x8 bfr[4];
#pragma unroll
    for (int kks = 0; kks < 4; ++kks)
        bfr[kks] = __builtin_bit_cast(bf16x8,
            *(const short8*)(WeTf + (size_t)((((nt << 2) + kks) << 6) + lane) * 8));
    float zl = ld1(zv, fz, nt * 16 + mrow);
    const float* pbcol = pbT + (size_t)(nt * 16 + mrow) * SP_;

    __syncthreads();

    // --- scores: 13 m-tiles x (4 MFMA) -> tanh -> z-dot -> quad-reduce -> sp ---
    float* sp = smemU;   // [8][SP_]
    for (int mt = 0; mt < 13; ++mt) {
        floatx4 acc = {0.f, 0.f, 0.f, 0.f};
        int r = mt * 16 + mrow;
        int rbase = r * D_, rx = (r & 7) << 3;
#pragma unroll
        for (int kks = 0; kks < 4; ++kks) {
            bf16x8 af = __builtin_bit_cast(bf16x8,
                *(const short8*)(Xsh + rbase + ((kks * 32 + quad * 8) ^ rx)));
            acc = __builtin_amdgcn_mfma_f32_16x16x32_bf16(af, bfr[kks], acc, 0, 0, 0);
        }
        float4 pbq = *(const float4*)(pbcol + mt * 16 + quad * 4);
#pragma unroll
        for (int reg = 0; reg < 4; ++reg) {
            float val = fast_tanh(acc[reg] + (&pbq.x)[reg]) * zl;
            val += __shfl_xor(val, 1, 64);
            val += __shfl_xor(val, 2, 64);
            val += __shfl_xor(val, 4, 64);
            val += __shfl_xor(val, 8, 64);
            int s = mt * 16 + quad * 4 + reg;
            if (mrow == 0 && s < S_) sp[nt * SP_ + s] = val;
        }
    }
    __syncthreads();

    float myscore = -INFINITY;
    if (t < S_) {
        float ss = 0.f;
#pragma unroll
        for (int w8 = 0; w8 < 8; ++w8) ss += sp[w8 * SP_ + t];
        myscore = ss;
    }

    // --- length via ballot (contiguous prefix) ---
    int nz = 0;
    if (t < S_)
        nz = fMk ? (((const unsigned char*)maskv)[(size_t)b * S_ + t] != 0)
                 : (((const int*)maskv)[(size_t)b * S_ + t] != 0);
    unsigned long long bal = __ballot(nz);
    if (lane == 0) redi[wv] = __popcll(bal);
    __syncthreads();
    int length = redi[0] + redi[1] + redi[2] + redi[3]
               + redi[4] + redi[5] + redi[6] + redi[7];   // >= 1
    int last = length - 1;

    // --- softmax over valid prefix ---
    float sc = (t < length) ? myscore : -INFINITY;
    float m = sc;
    for (int off = 32; off; off >>= 1) m = fmaxf(m, __shfl_xor(m, off, 64));
    if (lane == 0) red[wv] = m;
    __syncthreads();
    if (t == 0) {
        float mm = red[0];
#pragma unroll
        for (int i = 1; i < 8; ++i) mm = fmaxf(mm, red[i]);
        sc1s = mm;
    }
    __syncthreads();
    float e = (t < length) ? expf(sc - sc1s) : 0.f;
    float rr = e;
    for (int off = 32; off; off >>= 1) rr += __shfl_xor(rr, off, 64);
    __syncthreads();
    if (lane == 0) red[wv] = rr;
    __syncthreads();
    if (t == 0) {
        float ssum = 0.f;
#pragma unroll
        for (int i = 0; i < 8; ++i) ssum += red[i];
        sc2s = ssum;
    }
    __syncthreads();
    if (t < 256) attn[t] = e / sc2s;    // 0 beyond length
    __syncthreads();

    // --- attention_output[d] = sum_s attn[s]*X[b,s,d] (X from LDS on bf16 path) ---
    float* partial = smemU;   // [16][128]
    {
        int spi = t >> 5, d4 = (t & 31) * 4;
        float a0 = 0.f, a1 = 0.f, a2 = 0.f, a3 = 0.f;
        if (fXs) {
            for (int s = spi; s < S_; s += 16) {
                float ww = attn[s];
                uint2 u = *(const uint2*)(Xsh + s * D_ + (d4 ^ ((s & 7) << 3)));
                a0 = fmaf(ww, bf2f((unsigned short)(u.x & 0xffff)), a0);
                a1 = fmaf(ww, bf2f((unsigned short)(u.x >> 16)), a1);
                a2 = fmaf(ww, bf2f((unsigned short)(u.y & 0xffff)), a2);
                a3 = fmaf(ww, bf2f((unsigned short)(u.y >> 16)), a3);
            }
        } else {
            for (int s = spi; s < S_; s += 16) {
                float ww = attn[s];
                float4 u = *(const float4*)((const float*)Xs + ((size_t)b * S_ + s) * D_ + d4);
                a0 = fmaf(ww, u.x, a0); a1 = fmaf(ww, u.y, a1);
                a2 = fmaf(ww, u.z, a2); a3 = fmaf(ww, u.w, a3);
            }
        }
        partial[spi * D_ + d4 + 0] = a0;
        partial[spi * D_ + d4 + 1] = a1;
        partial[spi * D_ + d4 + 2] = a2;
        partial[spi * D_ + d4 + 3] = a3;
    }
    __syncthreads();
    if (t < D_) {
        float v = 0.f;
#pragma unroll
        for (int p = 0; p < 16; ++p) v += partial[p * D_ + t];
        att_out[t] = v;
        float xl = fXs ? bf2f(Xsh[last * D_ + (t ^ ((last & 7) << 3))])
                       : ((const float*)Xs)[((size_t)b * S_ + last) * D_ + t];
        float lv = attn[last] * xl;
        lastv[t] = lv;
        outv[t] = v - lv;       // out_vec = attention_output - last_vec
    }
    __syncthreads();

    // --- inner = dot(att_out, X_item[b]); write concated row (f32) ---
    {
        float pi = (t < D_) ? att_out[t] * ld1(Xitem, fXi, (size_t)b * D_ + t) : 0.f;
        for (int off = 32; off; off >>= 1) pi += __shfl_xor(pi, off, 64);
        if (lane == 0) red[wv] = pi;
        __syncthreads();
        if (t < D_) out[(size_t)b * (D_ + 1) + t] = att_out[t];
        if (t == 0) {
            float s8 = 0.f;
#pragma unroll
            for (int i = 0; i < 8; ++i) s8 += red[i];
            out[(size_t)b * (D_ + 1) + D_] = s8;
        }
        __syncthreads();
    }

    // --- pos loss: cos(last_vec, out_vec) ---
    {
        float l_ = (t < D_) ? lastv[t] : 0.f;
        float o_ = (t < D_) ? outv[t] : 0.f;
        float r0 = l_ * l_, r1 = l_ * o_, r2 = o_ * o_;
        for (int off = 32; off; off >>= 1) {
            r0 += __shfl_xor(r0, off, 64);
            r1 += __shfl_xor(r1, off, 64);
            r2 += __shfl_xor(r2, off, 64);
        }
        if (lane == 0) { red[wv] = r0; red[8 + wv] = r1; red[16 + wv] = r2; }
        __syncthreads();
        if (t == 0) {
            float ll = 0.f, lo = 0.f, oo = 0.f;
#pragma unroll
            for (int i = 0; i < 8; ++i) { ll += red[i]; lo += red[8 + i]; oo += red[16 + i]; }
            float cosv = lo / (sqrtf(fmaxf(ll, 1e-12f)) * sqrtf(fmaxf(oo, 1e-12f)));
            float pl = 0.5f * (1.f - cosv);
            pos_loss[b] = log1pf(expf(-pl));
            vvs = oo;
        }
        __syncthreads();
    }

    // --- neg losses: thread (nn,part) computes eighth-dot; LDS reduce ---
    {
        float* p_oo = smemU;          // [8][64]
        float* p_ov = smemU + 512;    // [8][64]
        float o_oo = 0.f, o_ov = 0.f;
#pragma unroll
        for (int j = 0; j < 16; ++j) {
            float wv_ = outv[part * 16 + j];
            o_oo = fmaf(o_f[j], o_f[j], o_oo);
            o_ov = fmaf(o_f[j], wv_, o_ov);
        }
        p_oo[part * 64 + nn] = o_oo;
        p_ov[part * 64 + nn] = o_ov;
        __syncthreads();
        if (t < 64) {
            float oo = 0.f, ov = 0.f;
#pragma unroll
            for (int p8 = 0; p8 < 8; ++p8) { oo += p_oo[p8 * 64 + t]; ov += p_ov[p8 * 64 + t]; }
            float cosn = ov / (sqrtf(fmaxf(oo, 1e-12f)) * sqrtf(fmaxf(vvs, 1e-12f)));
            float nl = 0.5f * (1.f - cosn);
            float nloss = log1pf(expf(nl));
            for (int off = 32; off; off >>= 1) nloss += __shfl_xor(nloss, off, 64);
            if (t == 0) neg_sum[b] = nloss;
        }
    }
}

// ---------------- K3: aux[b] = sum_b'(pos_loss) + neg_sum[b] (f32) ----------------
__global__ __launch_bounds__(1024) void final_kernel(
    const float* __restrict__ pos_loss,
    const float* __restrict__ neg_sum,
    float* __restrict__ out)
{
    __shared__ float red[16];
    int t = threadIdx.x;
    float v = pos_loss[t];
    for (int off = 32; off; off >>= 1) v += __shfl_xor(v, off, 64);
    if ((t & 63) == 0) red[t >> 6] = v;
    __syncthreads();
    if (t == 0) {
        float s = 0.f;
#pragma unroll
        for (int i = 0; i < 16; ++i) s += red[i];
        red[0] = s;
    }
    __syncthreads();
    out[(size_t)B_ * (D_ + 1) + t] = red[0] + neg_sum[t];
}

extern "C" void kernel_launch(void* const* d_in, const int* in_sizes, int n_in,
                              void* d_out, int out_size, void* d_ws, size_t ws_size,
                              hipStream_t stream) {
    const void* Xs     = d_in[0]; // X_series [B,S,D]
    const void* pos    = d_in[1]; // pos_series [S,D]
    const void* Xitem  = d_in[2]; // X_item [B,D]
    const void* mask   = d_in[3]; // valid_mask [B,S]
    const void* origin = d_in[4]; // origin [B,N,D]
    const void* Wp     = d_in[5]; // [D,H]
    const void* We     = d_in[6]; // [D,H]
    const void* zv     = d_in[7]; // [H]

    int*   flags    = (int*)d_ws;                                  // 128 B
    unsigned short* WeTf = (unsigned short*)((char*)d_ws + 128);   // 32 KB swizzled
    float* pbT      = (float*)((char*)d_ws + 128 + 32768);         // 128*208 f32 (transposed, padded)
    float* pos_loss = pbT + (size_t)H_ * SP_;                      // 1024 f32
    float* neg_sum  = pos_loss + B_;                               // 1024 f32
    float* out = (float*)d_out;                                    // f32 output

    detect_kernel<<<8, 64, 0, stream>>>(Xs, pos, Xitem, mask, origin, Wp, We, zv, flags);
    prep_kernel<<<201, 128, 0, stream>>>(We, pos, Wp, flags, WeTf, pbT);
    fused_kernel<<<B_, 512, 0, stream>>>(Xs, Xitem, mask, origin, WeTf, pbT, zv, flags,
                                         pos_loss, neg_sum, out);
    final_kernel<<<1, 1024, 0, stream>>>(pos_loss, neg_sum, out);
}

// Round 2
// 236.462 us; speedup vs baseline: 1.1297x; 1.1297x over previous
//
#include <hip/hip_runtime.h>
#include <hip/hip_bf16.h>
#include <math.h>

#define B_ 1024
#define S_ 200
#define D_ 128
#define H_ 128
#define N_ 64
#define SP_ 208   // S padded to 13*16 MFMA rows

typedef __attribute__((ext_vector_type(8))) short short8;
typedef __attribute__((ext_vector_type(8))) __bf16 bf16x8;
typedef __attribute__((ext_vector_type(4))) float floatx4;

typedef __attribute__((address_space(1))) void gvoid_t;
typedef __attribute__((address_space(3))) void lvoid_t;

static __device__ __forceinline__ float bf2f(unsigned short u) {
    union { unsigned int i; float f; } v; v.i = ((unsigned int)u) << 16; return v.f;
}
static __device__ __forceinline__ unsigned short f2bf(float f) {
    union { float f; unsigned int u; } v; v.f = f;
    unsigned int u = v.u;
    return (unsigned short)((u + 0x7FFFu + ((u >> 16) & 1u)) >> 16);   // RNE
}
static __device__ __forceinline__ float ld1(const void* p, int isbf, size_t i) {
    return isbf ? bf2f(((const unsigned short*)p)[i]) : ((const float*)p)[i];
}
static __device__ __forceinline__ float fast_tanh(float x) {
    float t = __expf(2.0f * x);
    return 1.0f - 2.0f * __builtin_amdgcn_rcpf(t + 1.0f);   // err ~2e-5
}
static __device__ __forceinline__ void gload_lds16(const void* g, void* l) {
    __builtin_amdgcn_global_load_lds((const gvoid_t*)g, (lvoid_t*)l, 16, 0, 0);
}

// ---- wave-local dtype detection (no barriers; every wave computes the same flag) ----
static __device__ __forceinline__ int detect_wave_256(const void* p) {
    int lane = threadIdx.x & 63;
    uint4 w = ((const uint4*)p)[lane];          // 256 words sampled per wave
    unsigned int ws[4] = {w.x, w.y, w.z, w.w};
    int pass = 0;
#pragma unroll
    for (int k = 0; k < 4; ++k) {
        unsigned int e = (ws[k] >> 7) & 0xFF;   // exponent of lo-bf16 if data is bf16
        pass += (e == 0 || (e >= 96 && e <= 140)) ? 1 : 0;
    }
#pragma unroll
    for (int off = 32; off; off >>= 1) pass += __shfl_xor(pass, off, 64);
    return pass * 4 >= 256 * 3;
}
static __device__ __forceinline__ int detect_wave_64(const void* p) {
    int lane = threadIdx.x & 63;
    unsigned int w = ((const unsigned int*)p)[lane];   // 64 words
    unsigned int e = (w >> 7) & 0xFF;
    int pass = (e == 0 || (e >= 96 && e <= 140)) ? 1 : 0;
#pragma unroll
    for (int off = 32; off; off >>= 1) pass += __shfl_xor(pass, off, 64);
    return pass * 4 >= 64 * 3;
}
static __device__ __forceinline__ int detect_mask_u8(const void* p) {
    int lane = threadIdx.x & 63;
    uint4 w = ((const uint4*)p)[lane];          // first 1 KB of mask
    unsigned int x = (w.x | w.y | w.z | w.w) & 0xFFFFFF00u;  // nonzero high bytes => u8
    return (__ballot(x != 0) != 0ULL) ? 1 : 0;
}

// ---------------- prep: block 0 -> WeTf (fragment-swizzled); blocks 1..200 -> pbL rows ----
// WeTf layout: frag = nt*4+kks; WeTf[(frag*64+lane)*8+j] = We[kks*32+(lane>>4)*8+j][nt*16+(lane&15)]
// pbL layout (per-lane C-fragment order): float idx ((mt*8+nt)*64 + quad*16 + mrow)*4 + reg
//   = pb[s = mt*16+quad*4+reg][h = nt*16+mrow]. s>=200 entries left unwritten (inert).
__global__ __launch_bounds__(128) void prep_kernel(
    const void* __restrict__ We, const void* __restrict__ pos,
    const void* __restrict__ Wp,
    unsigned short* __restrict__ WeTf, float* __restrict__ pbL)
{
    int blk = blockIdx.x, t = threadIdx.x;
    __shared__ unsigned short T[128][136];
    __shared__ float prow[D_];
    __shared__ int fl[2];
    if (blk == 0) {
        if (t < 64) { int f = detect_wave_256(We); if (t == 0) fl[0] = f; }
        __syncthreads();
        int fWe = fl[0];
        for (int c = t; c < 2048; c += 128) {
            int d = c >> 4, h8 = (c & 15) * 8;
            short8 v;
            if (fWe) {
                v = *(const short8*)((const unsigned short*)We + d * H_ + h8);
            } else {
                const float* p = (const float*)We + d * H_ + h8;
                float4 a = ((const float4*)p)[0], b = ((const float4*)p)[1];
                v[0] = (short)f2bf(a.x); v[1] = (short)f2bf(a.y);
                v[2] = (short)f2bf(a.z); v[3] = (short)f2bf(a.w);
                v[4] = (short)f2bf(b.x); v[5] = (short)f2bf(b.y);
                v[6] = (short)f2bf(b.z); v[7] = (short)f2bf(b.w);
            }
            *(short8*)(&T[d][h8]) = v;
        }
        __syncthreads();
        for (int i = t; i < 2048; i += 128) {
            int frag = i >> 6, ln = i & 63;
            int nt = frag >> 2, kks = frag & 3;
            int h = nt * 16 + (ln & 15);
            int dbase = kks * 32 + (ln >> 4) * 8;
            short8 v;
#pragma unroll
            for (int j = 0; j < 8; ++j) v[j] = (short)T[dbase + j][h];
            *(short8*)(WeTf + (size_t)i * 8) = v;
        }
    } else {
        if (t < 64)       { int f = detect_wave_256(pos); if (t == 0)  fl[0] = f; }
        else if (t < 128) { int f = detect_wave_256(Wp);  if (t == 64) fl[1] = f; }
        __syncthreads();
        int fPos = fl[0], fWp = fl[1];
        int s = blk - 1, h = t;
        prow[h] = ld1(pos, fPos, (size_t)s * D_ + h);
        __syncthreads();
        float acc = 0.f;
        if (fWp) {
            const unsigned short* W = (const unsigned short*)Wp;
            for (int d = 0; d < D_; ++d) acc = fmaf(prow[d], bf2f(W[d * H_ + h]), acc);
        } else {
            const float* W = (const float*)Wp;
            for (int d = 0; d < D_; ++d) acc = fmaf(prow[d], W[d * H_ + h], acc);
        }
        int mt = s >> 4, qr = s & 15;
        int idx = (((mt * 8 + (h >> 4)) * 64 + (qr >> 2) * 16 + (h & 15)) << 2) + (qr & 3);
        pbL[idx] = acc;
    }
}

// ---------------- fused: per-b scores GEMM + softmax + weighted sum + losses ----------------
// Block = 512 thr (8 waves), one b per block. X[b] staged via global_load_lds with
// pre-swizzled SOURCE address (LDS dest linear): LDS elem (s,x) holds X[s][x ^ ((s&7)<<3)].
__global__ __launch_bounds__(512, 4) void fused_kernel(
    const void* __restrict__ Xs, const void* __restrict__ Xitem,
    const void* __restrict__ maskv, const void* __restrict__ origin,
    const unsigned short* __restrict__ WeTf, const float* __restrict__ pbL,
    const void* __restrict__ zv,
    float* __restrict__ pos_loss, float* __restrict__ neg_sum,
    float* __restrict__ out)
{
    int b = blockIdx.x, t = threadIdx.x;
    int wv = t >> 6, lane = t & 63;
    int quad = lane >> 4, mrow = lane & 15;

    __shared__ __align__(16) unsigned short Xsh[SP_ * D_];   // 53248 B (rows 200..207 uninit, inert)
    __shared__ __align__(16) float partial[4096];            // sp[8][208] | partial[32][128] | p_oo/p_ov
    __shared__ float red4[512];
    __shared__ float attn[256];
    __shared__ float outv[D_];
    __shared__ float red[32];
    __shared__ int redi[8];

    // --- self-detect dtypes: every wave, fixed sample regions, no barrier ---
    int fXs = detect_wave_256(Xs);
    int fXi = detect_wave_256(Xitem);
    int fOr = detect_wave_256(origin);
    int fz  = detect_wave_64(zv);
    int fMk = detect_mask_u8(maskv);

    // --- stage X[b] -> LDS (swizzled). bf16: global_load_lds, source pre-swizzled ---
    if (fXs) {
        const unsigned short* gb = (const unsigned short*)Xs + (size_t)b * (S_ * D_);
        for (int i = t; i < S_ * 16; i += 512) {
            int s = i >> 4, c8 = (i & 15) * 8;
            int cs = c8 ^ ((s & 7) << 3);
            gload_lds16(gb + (size_t)s * D_ + cs, Xsh + (size_t)i * 8);
        }
    } else {
        const float* gb = (const float*)Xs + (size_t)b * (S_ * D_);
        for (int i = t; i < S_ * 16; i += 512) {
            int s = i >> 4, c8 = (i & 15) * 8;
            const float* p = gb + (size_t)s * D_ + c8;
            float4 a = ((const float4*)p)[0], c = ((const float4*)p)[1];
            short8 v;
            v[0] = (short)f2bf(a.x); v[1] = (short)f2bf(a.y);
            v[2] = (short)f2bf(a.z); v[3] = (short)f2bf(a.w);
            v[4] = (short)f2bf(c.x); v[5] = (short)f2bf(c.y);
            v[6] = (short)f2bf(c.z); v[7] = (short)f2bf(c.w);
            *(short8*)(Xsh + s * D_ + (c8 ^ ((s & 7) << 3))) = v;
        }
    }

    // --- early preloads while staging is in flight ---
    int nn = t >> 3, part = t & 7;       // thread -> (n, eighth-of-D)
    float o_f[16];
    if (fOr) {
        const unsigned short* p = (const unsigned short*)origin + ((size_t)b * N_ + nn) * D_ + part * 16;
#pragma unroll
        for (int j = 0; j < 2; ++j) {
            uint4 u = *(const uint4*)(p + j * 8);
            o_f[j*8+0] = bf2f((unsigned short)(u.x & 0xffff));
            o_f[j*8+1] = bf2f((unsigned short)(u.x >> 16));
            o_f[j*8+2] = bf2f((unsigned short)(u.y & 0xffff));
            o_f[j*8+3] = bf2f((unsigned short)(u.y >> 16));
            o_f[j*8+4] = bf2f((unsigned short)(u.z & 0xffff));
            o_f[j*8+5] = bf2f((unsigned short)(u.z >> 16));
            o_f[j*8+6] = bf2f((unsigned short)(u.w & 0xffff));
            o_f[j*8+7] = bf2f((unsigned short)(u.w >> 16));
        }
    } else {
        const float* p = (const float*)origin + ((size_t)b * N_ + nn) * D_ + part * 16;
#pragma unroll
        for (int j = 0; j < 4; ++j) {
            float4 v = *(const float4*)(p + j * 4);
            o_f[j*4+0] = v.x; o_f[j*4+1] = v.y; o_f[j*4+2] = v.z; o_f[j*4+3] = v.w;
        }
    }
    float xiv = (t < D_) ? ld1(Xitem, fXi, (size_t)b * D_ + t) : 0.f;
    int nz = 0;
    if (t < S_)
        nz = fMk ? (((const unsigned char*)maskv)[(size_t)b * S_ + t] != 0)
                 : (((const int*)maskv)[(size_t)b * S_ + t] != 0);

    // --- this wave's B fragments + z + coalesced pb base ---
    int nt = wv;
    bf16x8 bfr[4];
#pragma unroll
    for (int kks = 0; kks < 4; ++kks)
        bfr[kks] = __builtin_bit_cast(bf16x8,
            *(const short8*)(WeTf + (size_t)((((nt << 2) + kks) << 6) + lane) * 8));
    float zl = ld1(zv, fz, nt * 16 + mrow);
    const float4* pbw = (const float4*)pbL + nt * 64 + lane;   // + mt*512 per m-tile
    float4 pbc = pbw[0];

    asm volatile("s_waitcnt vmcnt(0)" ::: "memory");
    __syncthreads();                                           // S1

    // --- scores: 13 m-tiles x 4 MFMA, pb prefetched one mt ahead ---
    float* sp = partial;   // [8][SP_]
    for (int mt = 0; mt < 13; ++mt) {
        float4 pbn = pbc;
        if (mt < 12) pbn = pbw[(size_t)(mt + 1) * 512];
        floatx4 acc = {0.f, 0.f, 0.f, 0.f};
        int r = mt * 16 + mrow;
        int rbase = r * D_, rx = (r & 7) << 3;
#pragma unroll
        for (int kks = 0; kks < 4; ++kks) {
            bf16x8 af = __builtin_bit_cast(bf16x8,
                *(const short8*)(Xsh + rbase + ((kks * 32 + quad * 8) ^ rx)));
            acc = __builtin_amdgcn_mfma_f32_16x16x32_bf16(af, bfr[kks], acc, 0, 0, 0);
        }
#pragma unroll
        for (int reg = 0; reg < 4; ++reg) {
            float val = fast_tanh(acc[reg] + (&pbc.x)[reg]) * zl;
            val += __shfl_xor(val, 1, 64);
            val += __shfl_xor(val, 2, 64);
            val += __shfl_xor(val, 4, 64);
            val += __shfl_xor(val, 8, 64);
            int s = mt * 16 + quad * 4 + reg;
            if (mrow == 0 && s < S_) sp[nt * SP_ + s] = val;
        }
        pbc = pbn;
    }
    __syncthreads();                                           // S2

    // --- per-s score, mask, softmax (mask-guarded: no length dependency) ---
    float myscore = -INFINITY;
    if (t < S_) {
        float ss = 0.f;
#pragma unroll
        for (int w8 = 0; w8 < 8; ++w8) ss += sp[w8 * SP_ + t];
        myscore = ss;
    }
    unsigned long long bal = __ballot(nz);
    float scv = nz ? myscore : -INFINITY;
    float m = scv;
#pragma unroll
    for (int off = 32; off; off >>= 1) m = fmaxf(m, __shfl_xor(m, off, 64));
    if (lane == 0) { red[wv] = m; redi[wv] = __popcll(bal); }
    __syncthreads();                                           // S3
    int length = redi[0] + redi[1] + redi[2] + redi[3]
               + redi[4] + redi[5] + redi[6] + redi[7];        // >= 1
    int last = length - 1;
    float mglob = red[0];
#pragma unroll
    for (int i = 1; i < 8; ++i) mglob = fmaxf(mglob, red[i]);
    float e = nz ? expf(myscore - mglob) : 0.f;
    float rr = e;
#pragma unroll
    for (int off = 32; off; off >>= 1) rr += __shfl_xor(rr, off, 64);
    if (lane == 0) red[8 + wv] = rr;
    __syncthreads();                                           // S4
    float ssum = red[8] + red[9] + red[10] + red[11]
               + red[12] + red[13] + red[14] + red[15];
    if (t < 256) attn[t] = e / ssum;                           // 0 beyond length
    __syncthreads();                                           // S5

    // --- attention_output: 16B LDS reads, 32 s-slices ---
    {
        int spi = t >> 4;          // 0..31
        int d8 = (t & 15) * 8;     // 0..120
        float a0 = 0.f, a1 = 0.f, a2 = 0.f, a3 = 0.f;
        float a4 = 0.f, a5 = 0.f, a6 = 0.f, a7 = 0.f;
        for (int s = spi; s < S_; s += 32) {
            float ww = attn[s];
            short8 v2 = *(const short8*)(Xsh + s * D_ + (d8 ^ ((s & 7) << 3)));
            a0 = fmaf(ww, bf2f((unsigned short)v2[0]), a0);
            a1 = fmaf(ww, bf2f((unsigned short)v2[1]), a1);
            a2 = fmaf(ww, bf2f((unsigned short)v2[2]), a2);
            a3 = fmaf(ww, bf2f((unsigned short)v2[3]), a3);
            a4 = fmaf(ww, bf2f((unsigned short)v2[4]), a4);
            a5 = fmaf(ww, bf2f((unsigned short)v2[5]), a5);
            a6 = fmaf(ww, bf2f((unsigned short)v2[6]), a6);
            a7 = fmaf(ww, bf2f((unsigned short)v2[7]), a7);
        }
        float4 w0 = {a0, a1, a2, a3}, w1 = {a4, a5, a6, a7};
        *(float4*)(partial + spi * D_ + d8)     = w0;
        *(float4*)(partial + spi * D_ + d8 + 4) = w1;
    }
    __syncthreads();                                           // S6
    {
        int g = t >> 7, d = t & 127;    // 4 groups x 128 d
        float sgp = 0.f;
#pragma unroll
        for (int p = 0; p < 8; ++p) sgp += partial[(g * 8 + p) * D_ + d];
        red4[g * D_ + d] = sgp;
    }
    __syncthreads();                                           // S7

    // --- att/lastv/outv in registers; out write; merged 4-way reduction ---
    if (t < D_) {
        float att = red4[t] + red4[D_ + t] + red4[2 * D_ + t] + red4[3 * D_ + t];
        float xl = bf2f(Xsh[last * D_ + (t ^ ((last & 7) << 3))]);
        float lv = attn[last] * xl;
        float ov = att - lv;                 // out_vec = attention_output - last_vec
        outv[t] = ov;
        out[(size_t)b * (D_ + 1) + t] = att;
        float r0 = att * xiv;                // inner
        float r1 = lv * lv, r2 = lv * ov, r3 = ov * ov;
#pragma unroll
        for (int off = 32; off; off >>= 1) {
            r0 += __shfl_xor(r0, off, 64);
            r1 += __shfl_xor(r1, off, 64);
            r2 += __shfl_xor(r2, off, 64);
            r3 += __shfl_xor(r3, off, 64);
        }
        if (lane == 0) { red[wv] = r0; red[8 + wv] = r1; red[16 + wv] = r2; red[24 + wv] = r3; }
    }
    __syncthreads();                                           // S8
    float vv = red[24] + red[25];            // ||out_vec||^2, needed by all for neg loss
    if (t == 0) {
        out[(size_t)b * (D_ + 1) + D_] = red[0] + red[1];
        float ll = red[8] + red[9], lo = red[16] + red[17];
        float cosv = lo / (sqrtf(fmaxf(ll, 1e-12f)) * sqrtf(fmaxf(vv, 1e-12f)));
        float pl = 0.5f * (1.f - cosv);
        pos_loss[b] = log1pf(expf(-pl));
    }

    // --- neg losses: thread (nn,part) eighth-dot; LDS reduce ---
    {
        float* p_oo = partial;          // [8][64]
        float* p_ov = partial + 512;    // [8][64]
        float o_oo = 0.f, o_ov = 0.f;
#pragma unroll
        for (int j = 0; j < 16; ++j) {
            float wv_ = outv[part * 16 + j];
            o_oo = fmaf(o_f[j], o_f[j], o_oo);
            o_ov = fmaf(o_f[j], wv_, o_ov);
        }
        p_oo[part * 64 + nn] = o_oo;
        p_ov[part * 64 + nn] = o_ov;
        __syncthreads();                                       // S9
        if (t < 64) {
            float oo = 0.f, ov2 = 0.f;
#pragma unroll
            for (int p8 = 0; p8 < 8; ++p8) { oo += p_oo[p8 * 64 + t]; ov2 += p_ov[p8 * 64 + t]; }
            float cosn = ov2 / (sqrtf(fmaxf(oo, 1e-12f)) * sqrtf(fmaxf(vv, 1e-12f)));
            float nl = 0.5f * (1.f - cosn);
            float nloss = log1pf(expf(nl));
#pragma unroll
            for (int off = 32; off; off >>= 1) nloss += __shfl_xor(nloss, off, 64);
            if (t == 0) neg_sum[b] = nloss;
        }
    }
}

// ---------------- K3: aux[b] = sum_b'(pos_loss) + neg_sum[b] (f32) ----------------
__global__ __launch_bounds__(1024) void final_kernel(
    const float* __restrict__ pos_loss,
    const float* __restrict__ neg_sum,
    float* __restrict__ out)
{
    __shared__ float red[16];
    int t = threadIdx.x;
    float v = pos_loss[t];
    for (int off = 32; off; off >>= 1) v += __shfl_xor(v, off, 64);
    if ((t & 63) == 0) red[t >> 6] = v;
    __syncthreads();
    if (t == 0) {
        float s = 0.f;
#pragma unroll
        for (int i = 0; i < 16; ++i) s += red[i];
        red[0] = s;
    }
    __syncthreads();
    out[(size_t)B_ * (D_ + 1) + t] = red[0] + neg_sum[t];
}

extern "C" void kernel_launch(void* const* d_in, const int* in_sizes, int n_in,
                              void* d_out, int out_size, void* d_ws, size_t ws_size,
                              hipStream_t stream) {
    const void* Xs     = d_in[0]; // X_series [B,S,D]
    const void* pos    = d_in[1]; // pos_series [S,D]
    const void* Xitem  = d_in[2]; // X_item [B,D]
    const void* mask   = d_in[3]; // valid_mask [B,S]
    const void* origin = d_in[4]; // origin [B,N,D]
    const void* Wp     = d_in[5]; // [D,H]
    const void* We     = d_in[6]; // [D,H]
    const void* zv     = d_in[7]; // [H]

    unsigned short* WeTf = (unsigned short*)d_ws;                  // 32 KB swizzled
    float* pbL      = (float*)((char*)d_ws + 32768);               // 13*8*64*4 f32 = 104 KB
    float* pos_loss = pbL + 13 * 8 * 64 * 4;                       // 1024 f32
    float* neg_sum  = pos_loss + B_;                               // 1024 f32
    float* out = (float*)d_out;                                    // f32 output

    prep_kernel<<<201, 128, 0, stream>>>(We, pos, Wp, WeTf, pbL);
    fused_kernel<<<B_, 512, 0, stream>>>(Xs, Xitem, mask, origin, WeTf, pbL, zv,
                                         pos_loss, neg_sum, out);
    final_kernel<<<1, 1024, 0, stream>>>(pos_loss, neg_sum, out);
}